// Round 8
// baseline (230.762 us; speedup 1.0000x reference)
//
#include <hip/hip_runtime.h>
#include <stdint.h>

#pragma clang fp contract(off)

#define NB   8
#define NM   1024
#define NGT  100
#define GRID 1024
#define BLK  512

typedef uint32_t u32;
typedef unsigned long long u64;

// ---------- Threefry-2x32 block (exact JAX schedule) ----------
__device__ __forceinline__ void tf2x32(u32 k0, u32 k1, u32 x0, u32 x1, u32& o0, u32& o1) {
    u32 k2 = k0 ^ k1 ^ 0x1BD11BDAu;
#define TFR(r) { x0 += x1; x1 = (x1 << r) | (x1 >> (32 - r)); x1 ^= x0; }
    x0 += k0; x1 += k1;
    TFR(13) TFR(15) TFR(26) TFR(6)
    x0 += k1; x1 += k2 + 1u;
    TFR(17) TFR(29) TFR(16) TFR(24)
    x0 += k2; x1 += k0 + 2u;
    TFR(13) TFR(15) TFR(26) TFR(6)
    x0 += k0; x1 += k1 + 3u;
    TFR(17) TFR(29) TFR(16) TFR(24)
    x0 += k1; x1 += k2 + 4u;
    TFR(13) TFR(15) TFR(26) TFR(6)
    x0 += k2; x1 += k0 + 5u;
#undef TFR
    o0 = x0; o1 = x1;
}

__device__ __forceinline__ u32 tf_bits32(u32 k0, u32 k1, u32 i) {
    u32 o0, o1;
    tf2x32(k0, k1, 0u, i, o0, o1);
    return o0 ^ o1;
}

__device__ __forceinline__ float bits2unif(u32 bits) {
    return __uint_as_float((bits >> 9) | 0x3f800000u) - 1.0f;
}

__device__ __forceinline__ void image_keys(int b, u32 k[4][2]) {
    u32 kb0, kb1;
    tf2x32(0u, 42u, 0u, (u32)b, kb0, kb1);               // split(key(42), 8)[b]
    for (int i = 0; i < 4; i++)
        tf2x32(kb0, kb1, 0u, (u32)i, k[i][0], k[i][1]);  // split(key_b, 4)[i]
}

__device__ __forceinline__ float unif_at(const u32 k[2], int i) {
    return bits2unif(tf_bits32(k[0], k[1], (u32)i));
}

// ---------- numpy pairwise blocked sum over exactly 24 f32 terms ----------
__device__ __forceinline__ float np_pw24(const float* t) {
    float r0 = (t[0] + t[8])  + t[16];
    float r1 = (t[1] + t[9])  + t[17];
    float r2 = (t[2] + t[10]) + t[18];
    float r3 = (t[3] + t[11]) + t[19];
    float r4 = (t[4] + t[12]) + t[20];
    float r5 = (t[5] + t[13]) + t[21];
    float r6 = (t[6] + t[14]) + t[22];
    float r7 = (t[7] + t[15]) + t[23];
    return ((r0 + r1) + (r2 + r3)) + ((r4 + r5) + (r6 + r7));
}

// monotone float -> u32 order map (no NaNs occur in our angle stream)
__device__ __forceinline__ u32 fkey(float f) {
    u32 b = __float_as_uint(f);
    return (b & 0x80000000u) ? ~b : (b | 0x80000000u);
}

// ---------- register-resident rotated 3D IoU (sorting network, no scratch) ----------
__device__ __forceinline__ float pair_iou_slow(const float* a, const float* b) {
    float oh = fminf(a[2] + a[5] * 0.5f, b[2] + b[5] * 0.5f)
             - fmaxf(a[2] - a[5] * 0.5f, b[2] - b[5] * 0.5f);
    oh = fmaxf(oh, 0.0f);
    float va = a[3] * a[4] * a[5];
    float vb = b[3] * b[4] * b[5];

    float ca = cosf(a[6]), sa = sinf(a[6]);
    float cb = cosf(b[6]), sb = sinf(b[6]);
    const float SX[4] = {1.f, 1.f, -1.f, -1.f};
    const float SY[4] = {1.f, -1.f, -1.f, 1.f};
    float axp[4], ayp[4], bxp[4], byp[4];
    float hx = a[3] * 0.5f, hy = a[4] * 0.5f;
    #pragma unroll
    for (int q = 0; q < 4; q++) {
        float lx = SX[q] * hx, ly = SY[q] * hy;
        axp[q] = lx * ca - ly * sa + a[0];
        ayp[q] = lx * sa + ly * ca + a[1];
    }
    hx = b[3] * 0.5f; hy = b[4] * 0.5f;
    #pragma unroll
    for (int q = 0; q < 4; q++) {
        float lx = SX[q] * hx, ly = SY[q] * hy;
        bxp[q] = lx * cb - ly * sb + b[0];
        byp[q] = lx * sb + ly * cb + b[1];
    }

    // 24 candidates at fixed positions: 16 crossings (i-major), 4 a-in-b, 4 b-in-a
    float vx[24], vy[24];
    u32 vm = 0;
    #pragma unroll
    for (int i = 0; i < 4; i++) {
        float a1x = axp[i], a1y = ayp[i];
        float d1x = axp[(i + 1) & 3] - a1x, d1y = ayp[(i + 1) & 3] - a1y;
        #pragma unroll
        for (int j = 0; j < 4; j++) {
            int pos = i * 4 + j;
            float b1x = bxp[j], b1y = byp[j];
            float d2x = bxp[(j + 1) & 3] - b1x, d2y = byp[(j + 1) & 3] - b1y;
            float fx = b1x - a1x, fy = b1y - a1y;
            float den = d1x * d2y - d1y * d2x;
            bool val = false; float px = 0.f, py = 0.f;
            if (fabsf(den) > 1e-8f) {
                float tt = (fx * d2y - fy * d2x) / den;
                float uu = (fx * d1y - fy * d1x) / den;
                if (tt >= 0.f && tt <= 1.f && uu >= 0.f && uu <= 1.f) {
                    val = true; px = a1x + tt * d1x; py = a1y + tt * d1y;
                }
            }
            vx[pos] = val ? px : 0.f;
            vy[pos] = val ? py : 0.f;
            vm |= (val ? 1u : 0u) << pos;
        }
    }
    #pragma unroll
    for (int q = 0; q < 4; q++) {
        float rx = axp[q] - b[0], ry = ayp[q] - b[1];
        float lx = rx * cb + ry * sb, ly = -rx * sb + ry * cb;
        bool v = (fabsf(lx) <= b[3] * 0.5f + 1e-6f) && (fabsf(ly) <= b[4] * 0.5f + 1e-6f);
        vx[16 + q] = v ? axp[q] : 0.f; vy[16 + q] = v ? ayp[q] : 0.f;
        vm |= (v ? 1u : 0u) << (16 + q);
    }
    #pragma unroll
    for (int q = 0; q < 4; q++) {
        float rx = bxp[q] - a[0], ry = byp[q] - a[1];
        float lx = rx * ca + ry * sa, ly = -rx * sa + ry * ca;
        bool v = (fabsf(lx) <= a[3] * 0.5f + 1e-6f) && (fabsf(ly) <= a[4] * 0.5f + 1e-6f);
        vx[20 + q] = v ? bxp[q] : 0.f; vy[20 + q] = v ? byp[q] : 0.f;
        vm |= (v ? 1u : 0u) << (20 + q);
    }

    int nv = __popc(vm);
    if (nv <= 2) return 0.0f;   // bit-exact: shoelace of <=2 pts sums to 0 in np pairwise too

    float cx = np_pw24(vx) / (float)nv;
    float cy = np_pw24(vy) / (float)nv;

    // sortable elements: key = (mapped angle, pos); payload rel coords
    u64 key[24]; float sx[24], sy[24];
    #pragma unroll
    for (int p = 0; p < 24; p++) {
        bool v = (vm >> p) & 1u;
        float rxx = vx[p] - cx, ryy = vy[p] - cy;
        sx[p] = v ? rxx : 0.f;
        sy[p] = v ? ryy : 0.f;
        float ang = atan2f(sy[p], sx[p]);
        u32 hi = v ? fkey(ang) : 0xFFFFFFFFu;   // invalid after all valid (ref uses 1e9)
        key[p] = ((u64)hi << 32) | (u64)(u32)p;
    }

    // Batcher odd-even mergesort, n=24, ascending (stable via pos in low bits)
#define CE(A, B) { \
        u64 ka = key[A], kb = key[B]; \
        bool sw = ka > kb; \
        float xa = sx[A], xb = sx[B], ya = sy[A], yb = sy[B]; \
        key[A] = sw ? kb : ka; key[B] = sw ? ka : kb; \
        sx[A]  = sw ? xb : xa; sx[B]  = sw ? xa : xb; \
        sy[A]  = sw ? yb : ya; sy[B]  = sw ? ya : yb; }
    #pragma unroll
    for (int pp = 1; pp < 24; pp <<= 1) {
        #pragma unroll
        for (int kq = pp; kq >= 1; kq >>= 1) {
            #pragma unroll
            for (int jq = kq % pp; jq + kq < 24; jq += 2 * kq) {
                #pragma unroll
                for (int iq = 0; iq < kq; iq++) {
                    if (iq + jq + kq < 24) {
                        if ((iq + jq) / (2 * pp) == (iq + jq + kq) / (2 * pp)) {
                            CE(iq + jq, iq + jq + kq);
                        }
                    }
                }
            }
        }
    }
#undef CE

    // shoelace terms at sorted positions; wrap at nv-1 to slot 0; tail = 0
    float st[24];
    #pragma unroll
    for (int i = 0; i < 24; i++) {
        const int nidx = (i + 1 < 24) ? (i + 1) : 0;
        bool wrap = (i + 1 >= nv);
        float nx2 = wrap ? sx[0] : sx[nidx];
        float ny2 = wrap ? sy[0] : sy[nidx];
        float c = sx[i] * ny2 - sy[i] * nx2;
        st[i] = (i < nv) ? c : 0.0f;
    }
    float area = 0.5f * fabsf(np_pw24(st));
    float inter = area * oh;
    return inter / fmaxf(va + vb - inter, 1e-6f);
}

// ---------- output layout (f32, return order) ----------
#define O_ROIS 0
#define O_GT   7168
#define O_IOU  15360
#define O_SC   16384
#define O_LB   17408
#define O_CLS  18432
#define O_REG  19456

// ---------- single fused kernel ----------
__global__ __launch_bounds__(BLK) void rcnn_one(
    const float* __restrict__ rois, const float* __restrict__ gts,
    const float* __restrict__ scores, const int* __restrict__ labels,
    float* __restrict__ mo, int* __restrict__ asgn, u32* __restrict__ done,
    float* __restrict__ out)
{
    __shared__ float s_gt[NGT * 8];
    __shared__ u32   s_buf[8][100];
    __shared__ u32   s_tk;
    __shared__ float s_mo[NM], s_u1[NM], s_ufg[NM];
    __shared__ int   s_fgc[NM], s_hardc[NM], s_easyc[NM], s_perm[NM];
    __shared__ int   s_wcf[16], s_wch[16], s_wce[16];
    __shared__ int   s_nfg, s_nhard, s_neasy;

    int t = threadIdx.x;
    int lane = t & 63, wid = t >> 6;
    u64 lm = (1ull << lane) - 1ull;

    // ================= A phase: wave-per-roi IoU max/argmax =================
    {
        int r = blockIdx.x * 8 + wid;          // roi id; blocks image-aligned (1024%8==0)
        int bimg = r >> 10;

        for (int i = t; i < NGT * 8; i += BLK) s_gt[i] = gts[(size_t)bimg * NGT * 8 + i];
        __syncthreads();

        float a[7];
        {
            const float* ap = rois + (size_t)r * 7;
            #pragma unroll
            for (int q = 0; q < 7; q++) a[q] = ap[q];
        }

        // exact reject (same FP expressions as reference): rounds g=lane, g=lane+64
        bool sv0 = false, sv1 = false;
        {
            const float* gp = &s_gt[lane * 8];
            float s8 = 0.f;
            #pragma unroll
            for (int q = 0; q < 8; q++) s8 += gp[q];
            if (s8 != 0.f) {
                float ohh = fminf(a[2] + a[5] * 0.5f, gp[2] + gp[5] * 0.5f)
                          - fmaxf(a[2] - a[5] * 0.5f, gp[2] - gp[5] * 0.5f);
                ohh = fmaxf(ohh, 0.f);
                float dx = a[0] - gp[0], dy = a[1] - gp[1];
                float ra = 0.5f * sqrtf(a[3] * a[3] + a[4] * a[4]);
                float rb = 0.5f * sqrtf(gp[3] * gp[3] + gp[4] * gp[4]);
                float rr = ra + rb + 1e-2f;
                sv0 = !(ohh <= 0.f || (dx * dx + dy * dy) > rr * rr);
            }
        }
        if (lane + 64 < NGT) {
            const float* gp = &s_gt[(lane + 64) * 8];
            float s8 = 0.f;
            #pragma unroll
            for (int q = 0; q < 8; q++) s8 += gp[q];
            if (s8 != 0.f) {
                float ohh = fminf(a[2] + a[5] * 0.5f, gp[2] + gp[5] * 0.5f)
                          - fmaxf(a[2] - a[5] * 0.5f, gp[2] - gp[5] * 0.5f);
                ohh = fmaxf(ohh, 0.f);
                float dx = a[0] - gp[0], dy = a[1] - gp[1];
                float ra = 0.5f * sqrtf(a[3] * a[3] + a[4] * a[4]);
                float rb = 0.5f * sqrtf(gp[3] * gp[3] + gp[4] * gp[4]);
                float rr = ra + rb + 1e-2f;
                sv1 = !(ohh <= 0.f || (dx * dx + dy * dy) > rr * rr);
            }
        }

        // in-wave survivor compaction (g ascending preserved)
        u64 m0 = __ballot(sv0), m1 = __ballot(sv1);
        int c0 = __popcll(m0);
        int s  = c0 + __popcll(m1);
        if (sv0) s_buf[wid][__popcll(m0 & lm)] = (u32)lane;
        if (sv1) s_buf[wid][c0 + __popcll(m1 & lm)] = (u32)(lane + 64);

        // dense slow path: survivors packed into low lanes, one exec per 64
        float bv = 0.0f; int bg = 0x7fffffff;
        for (int bs = 0; bs < s; bs += 64) {
            int i = bs + lane;
            bool act = i < s;
            int g = act ? (int)s_buf[wid][i] : 0;
            float gr[7];
            #pragma unroll
            for (int q = 0; q < 7; q++) gr[q] = s_gt[g * 8 + q];
            float v = 0.0f;
            if (act) v = pair_iou_slow(a, gr);
            int gg = act ? g : 0x7fffffff;
            if (v > bv || (v == bv && gg < bg)) { bv = v; bg = gg; }
        }
        // wave max/argmax, first-index-wins
        #pragma unroll
        for (int sh = 32; sh > 0; sh >>= 1) {
            float v2 = __shfl_down(bv, sh);
            int   g2 = __shfl_down(bg, sh);
            if (v2 > bv || (v2 == bv && g2 < bg)) { bv = v2; bg = g2; }
        }
        if (lane == 0) {
            mo[r]   = bv;
            asgn[r] = (bv == 0.0f) ? 0 : bg;   // max==0 -> argmax 0
        }
    }

    // ================= election: last 8 blocks run sampling =================
    __syncthreads();
    __threadfence();                            // release this block's mo/asgn
    if (t == 0) s_tk = atomicAdd(done, 1u);     // device-scope ticket
    __syncthreads();
    u32 tk = s_tk;
    if (tk < (u32)(GRID - 8)) return;
    int img = (GRID - 1) - (int)tk;             // 0..7
    if (t == 0) {
        while (__hip_atomic_load(done, __ATOMIC_ACQUIRE, __HIP_MEMORY_SCOPE_AGENT) < (u32)GRID)
            __builtin_amdgcn_s_sleep(32);
    }
    __syncthreads();
    __threadfence();                            // acquire all blocks' mo/asgn

    // ================= B phase: per-image sampling + gather =================
    {
        u32 kk[4][2];
        image_keys(img, kk);

        #pragma unroll
        for (int ps = 0; ps < 2; ps++) {
            int ti = ps * 512 + t;
            float mv = mo[(size_t)img * NM + ti];
            s_mo[ti] = mv;
            s_u1[ti] = unif_at(kk[0], ti);      // uniform(k1,(1024,))[ti]
            bool fg   = (mv >= 0.55f);
            bool easy = (mv < 0.1f);
            bool hard = (mv < 0.55f) && (mv >= 0.1f);
            u64 bf = __ballot(fg), bh = __ballot(hard), be = __ballot(easy);
            int cw = ps * 8 + wid;              // chunk 0..15 == rois [64cw,64cw+64)
            if (lane == 0) {
                s_wcf[cw] = __popcll(bf); s_wch[cw] = __popcll(bh); s_wce[cw] = __popcll(be);
            }
        }
        __syncthreads();
        if (t == 0) {
            int af = 0, ah = 0, ae = 0;
            for (int w = 0; w < 16; w++) {
                int cf = s_wcf[w], ch = s_wch[w], ce = s_wce[w];
                s_wcf[w] = af; s_wch[w] = ah; s_wce[w] = ae;
                af += cf; ah += ch; ae += ce;
            }
            s_nfg = af; s_nhard = ah; s_neasy = ae;
        }
        __syncthreads();
        #pragma unroll
        for (int ps = 0; ps < 2; ps++) {
            int ti = ps * 512 + t;
            float mv = s_mo[ti];
            bool fg   = (mv >= 0.55f);
            bool easy = (mv < 0.1f);
            bool hard = (mv < 0.55f) && (mv >= 0.1f);
            u64 bf = __ballot(fg), bh = __ballot(hard), be = __ballot(easy);
            int cw = ps * 8 + wid;
            if (fg)   { int p = s_wcf[cw] + __popcll(bf & lm); s_fgc[p] = ti; s_ufg[p] = s_u1[ti]; }
            if (hard) { int p = s_wch[cw] + __popcll(bh & lm); s_hardc[p] = ti; }
            if (easy) { int p = s_wce[cw] + __popcll(be & lm); s_easyc[p] = ti; }
        }
        __syncthreads();

        int n_fg = s_nfg, n_hard = s_nhard, n_easy = s_neasy;

        // fg_perm: fg indices stable-sorted by u1 (O(n_fg^2) rank)
        for (int i = t; i < n_fg; i += 512) {
            float ut = s_ufg[i];
            int rk = 0;
            for (int j = 0; j < n_fg; j++) {
                float uj = s_ufg[j];
                rk += (uj < ut) || (uj == ut && j < i);
            }
            s_perm[rk] = s_fgc[i];
        }
        __syncthreads();

        if (t < 128) {
            int j = t;
            int n_bg = n_hard + n_easy;
            int fg_this = (n_fg > 0) ? ((n_bg > 0) ? ((n_fg < 64) ? n_fg : 64) : 128) : 0;
            int bg_this = 128 - fg_this;

            int idx;
            if (j < fg_this) {
                if (n_bg > 0) {
                    idx = s_perm[j];
                } else {
                    float u2 = unif_at(kk[1], j);
                    int v = (int)(u2 * (float)n_fg);
                    if (v > n_fg - 1) v = n_fg - 1;
                    if (v < 0) v = 0;
                    idx = s_fgc[v];
                }
            } else {
                int hard_num;
                if (n_hard > 0 && n_easy > 0) hard_num = (int)((float)bg_this * 0.8f);
                else hard_num = (n_hard > 0) ? bg_this : 0;
                if (j - fg_this < hard_num) {
                    float u3 = unif_at(kk[2], j);
                    int v = (int)(u3 * (float)n_hard);
                    if (v > n_hard - 1) v = n_hard - 1;
                    if (v < 0) v = 0;
                    idx = s_hardc[v];
                } else {
                    if (n_easy > 0) {
                        float u4 = unif_at(kk[3], j);
                        int v = (int)(u4 * (float)n_easy);
                        if (v > n_easy - 1) v = n_easy - 1;
                        if (v < 0) v = 0;
                        idx = s_easyc[v];
                    } else {
                        idx = 0;
                    }
                }
            }
            if (idx < 0) idx = 0;
            if (idx > NM - 1) idx = NM - 1;

            float moj = s_mo[idx];
            int g = asgn[(size_t)img * NM + idx];
            if (g < 0) g = 0;
            if (g > NGT - 1) g = NGT - 1;

            size_t base = (size_t)img * 128 + j;
            const float* rp = rois + ((size_t)img * NM + idx) * 7;
            float* orp = out + O_ROIS + base * 7;
            for (int i = 0; i < 7; i++) orp[i] = rp[i];                       // exact f32 gather

            const float* gp = gts + ((size_t)img * NGT + g) * 8;
            float* ogp = out + O_GT + base * 8;
            for (int i = 0; i < 8; i++) ogp[i] = gp[i];                       // exact f32 gather

            out[O_IOU + base] = moj;
            out[O_SC + base]  = scores[(size_t)img * NM + idx];
            out[O_LB + base]  = (float)labels[(size_t)img * NM + idx];

            bool cfg = moj > 0.75f, cbg = moj < 0.25f;
            float cls = (!cfg && !cbg) ? (moj * 2.0f - 0.5f) : (cfg ? 1.0f : 0.0f);
            out[O_CLS + base] = cls;
            out[O_REG + base] = (moj > 0.55f) ? 1.0f : 0.0f;
        }
    }
}

extern "C" void kernel_launch(void* const* d_in, const int* in_sizes, int n_in,
                              void* d_out, int out_size, void* d_ws, size_t ws_size,
                              hipStream_t stream) {
    // identify inputs by element count (scores/labels tie resolved in dict order)
    const float* rois   = nullptr;
    const float* gts    = nullptr;
    const float* scores = nullptr;
    const int*   labels = nullptr;
    for (int i = 0; i < n_in; i++) {
        if (in_sizes[i] == NB * NM * 7)       rois = (const float*)d_in[i];
        else if (in_sizes[i] == NB * NGT * 8) gts  = (const float*)d_in[i];
        else if (in_sizes[i] == NB * NM) {
            if (!scores) scores = (const float*)d_in[i];
            else         labels = (const int*)d_in[i];
        }
    }
    float* out = (float*)d_out;  // 20480 f32, outputs concatenated in return order

    u32*   done = (u32*)d_ws;                                      // [0,4): ticket counter
    float* mo   = (float*)((char*)d_ws + 256);                     // 8192 f32
    int*   asg  = (int*)((char*)d_ws + 256 + NB * NM * 4);         // 8192 i32

    hipMemsetAsync(d_ws, 0, 4, stream);   // zero the ticket counter (in-graph memset node)
    rcnn_one<<<GRID, BLK, 0, stream>>>(rois, gts, scores, labels, mo, asg, done, out);
}

// Round 9
// 110.998 us; speedup vs baseline: 2.0790x; 2.0790x over previous
//
#include <hip/hip_runtime.h>
#include <stdint.h>

#pragma clang fp contract(off)

#define NB   8
#define NM   1024
#define NGT  100
#define RPB  16                  // rois per block (A phase)
#define BLK  256
#define GRID (NB * NM / RPB)     // 512, image-aligned (1024 % 16 == 0)

typedef uint32_t u32;
typedef unsigned long long u64;

// ---------- Threefry-2x32 block (exact JAX schedule) ----------
__device__ __forceinline__ void tf2x32(u32 k0, u32 k1, u32 x0, u32 x1, u32& o0, u32& o1) {
    u32 k2 = k0 ^ k1 ^ 0x1BD11BDAu;
#define TFR(r) { x0 += x1; x1 = (x1 << r) | (x1 >> (32 - r)); x1 ^= x0; }
    x0 += k0; x1 += k1;
    TFR(13) TFR(15) TFR(26) TFR(6)
    x0 += k1; x1 += k2 + 1u;
    TFR(17) TFR(29) TFR(16) TFR(24)
    x0 += k2; x1 += k0 + 2u;
    TFR(13) TFR(15) TFR(26) TFR(6)
    x0 += k0; x1 += k1 + 3u;
    TFR(17) TFR(29) TFR(16) TFR(24)
    x0 += k1; x1 += k2 + 4u;
    TFR(13) TFR(15) TFR(26) TFR(6)
    x0 += k2; x1 += k0 + 5u;
#undef TFR
    o0 = x0; o1 = x1;
}

__device__ __forceinline__ u32 tf_bits32(u32 k0, u32 k1, u32 i) {
    u32 o0, o1;
    tf2x32(k0, k1, 0u, i, o0, o1);
    return o0 ^ o1;
}

__device__ __forceinline__ float bits2unif(u32 bits) {
    return __uint_as_float((bits >> 9) | 0x3f800000u) - 1.0f;
}

__device__ __forceinline__ void image_keys(int b, u32 k[4][2]) {
    u32 kb0, kb1;
    tf2x32(0u, 42u, 0u, (u32)b, kb0, kb1);               // split(key(42), 8)[b]
    for (int i = 0; i < 4; i++)
        tf2x32(kb0, kb1, 0u, (u32)i, k[i][0], k[i][1]);  // split(key_b, 4)[i]
}

__device__ __forceinline__ float unif_at(const u32 k[2], int i) {
    return bits2unif(tf_bits32(k[0], k[1], (u32)i));
}

// ---------- numpy pairwise blocked sum over exactly 24 f32 terms ----------
__device__ __forceinline__ float np_pw24(const float* t) {
    float r0 = (t[0] + t[8])  + t[16];
    float r1 = (t[1] + t[9])  + t[17];
    float r2 = (t[2] + t[10]) + t[18];
    float r3 = (t[3] + t[11]) + t[19];
    float r4 = (t[4] + t[12]) + t[20];
    float r5 = (t[5] + t[13]) + t[21];
    float r6 = (t[6] + t[14]) + t[22];
    float r7 = (t[7] + t[15]) + t[23];
    return ((r0 + r1) + (r2 + r3)) + ((r4 + r5) + (r6 + r7));
}

// monotone float -> u32 order map (no NaNs in the angle stream)
__device__ __forceinline__ u32 fkey(float f) {
    u32 b = __float_as_uint(f);
    return (b & 0x80000000u) ? ~b : (b | 0x80000000u);
}

// ---------- register-resident rotated 3D IoU (verified bit-exact in R8) ----------
__device__ __forceinline__ float pair_iou_slow(const float* a, const float* b) {
    float oh = fminf(a[2] + a[5] * 0.5f, b[2] + b[5] * 0.5f)
             - fmaxf(a[2] - a[5] * 0.5f, b[2] - b[5] * 0.5f);
    oh = fmaxf(oh, 0.0f);
    float va = a[3] * a[4] * a[5];
    float vb = b[3] * b[4] * b[5];

    float ca = cosf(a[6]), sa = sinf(a[6]);
    float cb = cosf(b[6]), sb = sinf(b[6]);
    const float SX[4] = {1.f, 1.f, -1.f, -1.f};
    const float SY[4] = {1.f, -1.f, -1.f, 1.f};
    float axp[4], ayp[4], bxp[4], byp[4];
    float hx = a[3] * 0.5f, hy = a[4] * 0.5f;
    #pragma unroll
    for (int q = 0; q < 4; q++) {
        float lx = SX[q] * hx, ly = SY[q] * hy;
        axp[q] = lx * ca - ly * sa + a[0];
        ayp[q] = lx * sa + ly * ca + a[1];
    }
    hx = b[3] * 0.5f; hy = b[4] * 0.5f;
    #pragma unroll
    for (int q = 0; q < 4; q++) {
        float lx = SX[q] * hx, ly = SY[q] * hy;
        bxp[q] = lx * cb - ly * sb + b[0];
        byp[q] = lx * sb + ly * cb + b[1];
    }

    float vx[24], vy[24];
    u32 vm = 0;
    #pragma unroll
    for (int i = 0; i < 4; i++) {
        float a1x = axp[i], a1y = ayp[i];
        float d1x = axp[(i + 1) & 3] - a1x, d1y = ayp[(i + 1) & 3] - a1y;
        #pragma unroll
        for (int j = 0; j < 4; j++) {
            int pos = i * 4 + j;
            float b1x = bxp[j], b1y = byp[j];
            float d2x = bxp[(j + 1) & 3] - b1x, d2y = byp[(j + 1) & 3] - b1y;
            float fx = b1x - a1x, fy = b1y - a1y;
            float den = d1x * d2y - d1y * d2x;
            bool val = false; float px = 0.f, py = 0.f;
            if (fabsf(den) > 1e-8f) {
                float tt = (fx * d2y - fy * d2x) / den;
                float uu = (fx * d1y - fy * d1x) / den;
                if (tt >= 0.f && tt <= 1.f && uu >= 0.f && uu <= 1.f) {
                    val = true; px = a1x + tt * d1x; py = a1y + tt * d1y;
                }
            }
            vx[pos] = val ? px : 0.f;
            vy[pos] = val ? py : 0.f;
            vm |= (val ? 1u : 0u) << pos;
        }
    }
    #pragma unroll
    for (int q = 0; q < 4; q++) {
        float rx = axp[q] - b[0], ry = ayp[q] - b[1];
        float lx = rx * cb + ry * sb, ly = -rx * sb + ry * cb;
        bool v = (fabsf(lx) <= b[3] * 0.5f + 1e-6f) && (fabsf(ly) <= b[4] * 0.5f + 1e-6f);
        vx[16 + q] = v ? axp[q] : 0.f; vy[16 + q] = v ? ayp[q] : 0.f;
        vm |= (v ? 1u : 0u) << (16 + q);
    }
    #pragma unroll
    for (int q = 0; q < 4; q++) {
        float rx = bxp[q] - a[0], ry = byp[q] - a[1];
        float lx = rx * ca + ry * sa, ly = -rx * sa + ry * ca;
        bool v = (fabsf(lx) <= a[3] * 0.5f + 1e-6f) && (fabsf(ly) <= a[4] * 0.5f + 1e-6f);
        vx[20 + q] = v ? bxp[q] : 0.f; vy[20 + q] = v ? byp[q] : 0.f;
        vm |= (v ? 1u : 0u) << (20 + q);
    }

    int nv = __popc(vm);
    if (nv <= 2) return 0.0f;   // bit-exact: np pairwise shoelace of <=2 pts is 0

    float cx = np_pw24(vx) / (float)nv;
    float cy = np_pw24(vy) / (float)nv;

    u64 key[24]; float sx[24], sy[24];
    #pragma unroll
    for (int p = 0; p < 24; p++) {
        bool v = (vm >> p) & 1u;
        float rxx = vx[p] - cx, ryy = vy[p] - cy;
        sx[p] = v ? rxx : 0.f;
        sy[p] = v ? ryy : 0.f;
        float ang = atan2f(sy[p], sx[p]);
        u32 hi = v ? fkey(ang) : 0xFFFFFFFFu;
        key[p] = ((u64)hi << 32) | (u64)(u32)p;
    }

#define CE(A, B) { \
        u64 ka = key[A], kb = key[B]; \
        bool sw = ka > kb; \
        float xa = sx[A], xb = sx[B], ya = sy[A], yb = sy[B]; \
        key[A] = sw ? kb : ka; key[B] = sw ? ka : kb; \
        sx[A]  = sw ? xb : xa; sx[B]  = sw ? xa : xb; \
        sy[A]  = sw ? yb : ya; sy[B]  = sw ? ya : yb; }
    #pragma unroll
    for (int pp = 1; pp < 24; pp <<= 1) {
        #pragma unroll
        for (int kq = pp; kq >= 1; kq >>= 1) {
            #pragma unroll
            for (int jq = kq % pp; jq + kq < 24; jq += 2 * kq) {
                #pragma unroll
                for (int iq = 0; iq < kq; iq++) {
                    if (iq + jq + kq < 24) {
                        if ((iq + jq) / (2 * pp) == (iq + jq + kq) / (2 * pp)) {
                            CE(iq + jq, iq + jq + kq);
                        }
                    }
                }
            }
        }
    }
#undef CE

    float st[24];
    #pragma unroll
    for (int i = 0; i < 24; i++) {
        const int nidx = (i + 1 < 24) ? (i + 1) : 0;
        bool wrap = (i + 1 >= nv);
        float nx2 = wrap ? sx[0] : sx[nidx];
        float ny2 = wrap ? sy[0] : sy[nidx];
        float c = sx[i] * ny2 - sy[i] * nx2;
        st[i] = (i < nv) ? c : 0.0f;
    }
    float area = 0.5f * fabsf(np_pw24(st));
    float inter = area * oh;
    return inter / fmaxf(va + vb - inter, 1e-6f);
}

// ---------- output layout (f32, return order) ----------
#define O_ROIS 0
#define O_GT   7168
#define O_IOU  15360
#define O_SC   16384
#define O_LB   17408
#define O_CLS  18432
#define O_REG  19456

// LDS overlay: A phase and B phase never live simultaneously in a block
union SMem {
    struct {
        float gt[NGT * 9];          // padded rows: bank-conflict-free
        u32   list[RPB * NGT];
        float val[RPB * NGT];
        u32   mob[RPB];
        int   asg[RPB];
    } A;
    struct {
        float mo[NM], u1[NM], ufg[NM];
        int   fgc[NM], hardc[NM], easyc[NM], perm[NM];
        int   wcf[16], wch[16], wce[16];
        int   nfg, nhard, neasy;
    } B;
};

__global__ __launch_bounds__(BLK, 1) void rcnn_one(
    const float* __restrict__ rois, const float* __restrict__ gts,
    const float* __restrict__ scores, const int* __restrict__ labels,
    float* __restrict__ mo, int* __restrict__ asgn, u32* __restrict__ done,
    float* __restrict__ out)
{
    __shared__ SMem sm;
    __shared__ int  s_cnt;
    __shared__ u32  s_tk;

    int t = threadIdx.x;
    int lane = t & 63, wid = t >> 6;
    u64 lm = (1ull << lane) - 1ull;

    // ================= A phase: 16 rois x 100 gts per block =================
    {
        int base = blockIdx.x * RPB;            // first roi of this block
        int bimg = base >> 10;                  // all RPB rois share one image

        if (t == 0) s_cnt = 0;
        if (t < RPB) { sm.A.mob[t] = 0u; sm.A.asg[t] = 0x7fffffff; }
        for (int i = t; i < NGT * 8; i += BLK)
            sm.A.gt[(i >> 3) * 9 + (i & 7)] = gts[(size_t)bimg * NGT * 8 + i];
        __syncthreads();

        // phase 1: exact reject over 1600 pairs
        for (int p = t; p < RPB * NGT; p += BLK) {
            int rl = p / NGT;
            int g  = p - rl * NGT;
            const float* gp = &sm.A.gt[g * 9];
            float s8 = 0.f;
            #pragma unroll
            for (int q = 0; q < 8; q++) s8 += gp[q];
            if (s8 != 0.f) {
                const float* ap = rois + (size_t)(base + rl) * 7;
                float ohh = fminf(ap[2] + ap[5] * 0.5f, gp[2] + gp[5] * 0.5f)
                          - fmaxf(ap[2] - ap[5] * 0.5f, gp[2] - gp[5] * 0.5f);
                ohh = fmaxf(ohh, 0.f);
                float dx = ap[0] - gp[0], dy = ap[1] - gp[1];
                float ra = 0.5f * sqrtf(ap[3] * ap[3] + ap[4] * ap[4]);
                float rb = 0.5f * sqrtf(gp[3] * gp[3] + gp[4] * gp[4]);
                float rr = ra + rb + 1e-2f;
                if (!(ohh <= 0.f || (dx * dx + dy * dy) > rr * rr)) {
                    int pos = atomicAdd(&s_cnt, 1);
                    sm.A.list[pos] = ((u32)rl << 7) | (u32)g;
                }
            }
        }
        __syncthreads();
        int cnt = s_cnt;

        // phase 2: dense slow path (~21 survivors -> 1 wave exec, ~21 lanes)
        for (int i = t; i < cnt; i += BLK) {
            u32 pid = sm.A.list[i];
            int rl = (int)(pid >> 7);
            int g  = (int)(pid & 127u);
            float a[7], gr[7];
            const float* ap = rois + (size_t)(base + rl) * 7;
            #pragma unroll
            for (int q = 0; q < 7; q++) a[q] = ap[q];
            #pragma unroll
            for (int q = 0; q < 7; q++) gr[q] = sm.A.gt[g * 9 + q];
            float v = pair_iou_slow(a, gr);
            sm.A.val[i] = v;
            atomicMax(&sm.A.mob[rl], __float_as_uint(v));   // v >= 0: bit order == float order
        }
        __syncthreads();
        // argmax pass: smallest g among bit-equal winners
        for (int i = t; i < cnt; i += BLK) {
            u32 pid = sm.A.list[i];
            int rl = (int)(pid >> 7);
            int g  = (int)(pid & 127u);
            u32 vb = __float_as_uint(sm.A.val[i]);
            if (vb != 0u && vb == sm.A.mob[rl]) atomicMin(&sm.A.asg[rl], g);
        }
        __syncthreads();
        if (t < RPB) {
            u32 mb = sm.A.mob[t];
            mo[base + t]   = __uint_as_float(mb);
            asgn[base + t] = (mb == 0u) ? 0 : sm.A.asg[t];  // max==0 -> argmax 0
        }
    }

    // ================= election: last 8 blocks run sampling =================
    __syncthreads();
    __threadfence();
    if (t == 0) s_tk = atomicAdd(done, 1u);
    __syncthreads();
    u32 tk = s_tk;
    if (tk < (u32)(GRID - 8)) return;
    int img = (GRID - 1) - (int)tk;             // 0..7
    if (t == 0) {
        while (__hip_atomic_load(done, __ATOMIC_ACQUIRE, __HIP_MEMORY_SCOPE_AGENT) < (u32)GRID)
            __builtin_amdgcn_s_sleep(32);
    }
    __syncthreads();
    __threadfence();

    // ================= B phase: per-image sampling + gather =================
    {
        u32 kk[4][2];
        image_keys(img, kk);

        #pragma unroll
        for (int ps = 0; ps < 4; ps++) {
            int ti = ps * BLK + t;
            float mv = mo[(size_t)img * NM + ti];
            sm.B.mo[ti] = mv;
            sm.B.u1[ti] = unif_at(kk[0], ti);   // uniform(k1,(1024,))[ti]
            bool fg   = (mv >= 0.55f);
            bool easy = (mv < 0.1f);
            bool hard = (mv < 0.55f) && (mv >= 0.1f);
            u64 bf = __ballot(fg), bh = __ballot(hard), be = __ballot(easy);
            int cw = ps * 4 + wid;              // 16 chunks of 64 rois
            if (lane == 0) {
                sm.B.wcf[cw] = __popcll(bf); sm.B.wch[cw] = __popcll(bh); sm.B.wce[cw] = __popcll(be);
            }
        }
        __syncthreads();
        if (t == 0) {
            int af = 0, ah = 0, ae = 0;
            for (int w = 0; w < 16; w++) {
                int cf = sm.B.wcf[w], ch = sm.B.wch[w], ce = sm.B.wce[w];
                sm.B.wcf[w] = af; sm.B.wch[w] = ah; sm.B.wce[w] = ae;
                af += cf; ah += ch; ae += ce;
            }
            sm.B.nfg = af; sm.B.nhard = ah; sm.B.neasy = ae;
        }
        __syncthreads();
        #pragma unroll
        for (int ps = 0; ps < 4; ps++) {
            int ti = ps * BLK + t;
            float mv = sm.B.mo[ti];
            bool fg   = (mv >= 0.55f);
            bool easy = (mv < 0.1f);
            bool hard = (mv < 0.55f) && (mv >= 0.1f);
            u64 bf = __ballot(fg), bh = __ballot(hard), be = __ballot(easy);
            int cw = ps * 4 + wid;
            if (fg)   { int p = sm.B.wcf[cw] + __popcll(bf & lm); sm.B.fgc[p] = ti; sm.B.ufg[p] = sm.B.u1[ti]; }
            if (hard) { int p = sm.B.wch[cw] + __popcll(bh & lm); sm.B.hardc[p] = ti; }
            if (easy) { int p = sm.B.wce[cw] + __popcll(be & lm); sm.B.easyc[p] = ti; }
        }
        __syncthreads();

        int n_fg = sm.B.nfg, n_hard = sm.B.nhard, n_easy = sm.B.neasy;

        // fg_perm: fg indices stable-sorted by u1 (O(n_fg^2) rank)
        for (int i = t; i < n_fg; i += BLK) {
            float ut = sm.B.ufg[i];
            int rk = 0;
            for (int j = 0; j < n_fg; j++) {
                float uj = sm.B.ufg[j];
                rk += (uj < ut) || (uj == ut && j < i);
            }
            sm.B.perm[rk] = sm.B.fgc[i];
        }
        __syncthreads();

        if (t < 128) {
            int j = t;
            int n_bg = n_hard + n_easy;
            int fg_this = (n_fg > 0) ? ((n_bg > 0) ? ((n_fg < 64) ? n_fg : 64) : 128) : 0;
            int bg_this = 128 - fg_this;

            int idx;
            if (j < fg_this) {
                if (n_bg > 0) {
                    idx = sm.B.perm[j];
                } else {
                    float u2 = unif_at(kk[1], j);
                    int v = (int)(u2 * (float)n_fg);
                    if (v > n_fg - 1) v = n_fg - 1;
                    if (v < 0) v = 0;
                    idx = sm.B.fgc[v];
                }
            } else {
                int hard_num;
                if (n_hard > 0 && n_easy > 0) hard_num = (int)((float)bg_this * 0.8f);
                else hard_num = (n_hard > 0) ? bg_this : 0;
                if (j - fg_this < hard_num) {
                    float u3 = unif_at(kk[2], j);
                    int v = (int)(u3 * (float)n_hard);
                    if (v > n_hard - 1) v = n_hard - 1;
                    if (v < 0) v = 0;
                    idx = sm.B.hardc[v];
                } else {
                    if (n_easy > 0) {
                        float u4 = unif_at(kk[3], j);
                        int v = (int)(u4 * (float)n_easy);
                        if (v > n_easy - 1) v = n_easy - 1;
                        if (v < 0) v = 0;
                        idx = sm.B.easyc[v];
                    } else {
                        idx = 0;
                    }
                }
            }
            if (idx < 0) idx = 0;
            if (idx > NM - 1) idx = NM - 1;

            float moj = sm.B.mo[idx];
            int g = asgn[(size_t)img * NM + idx];
            if (g < 0) g = 0;
            if (g > NGT - 1) g = NGT - 1;

            size_t base = (size_t)img * 128 + j;
            const float* rp = rois + ((size_t)img * NM + idx) * 7;
            float* orp = out + O_ROIS + base * 7;
            for (int i = 0; i < 7; i++) orp[i] = rp[i];                       // exact f32 gather

            const float* gp = gts + ((size_t)img * NGT + g) * 8;
            float* ogp = out + O_GT + base * 8;
            for (int i = 0; i < 8; i++) ogp[i] = gp[i];                       // exact f32 gather

            out[O_IOU + base] = moj;
            out[O_SC + base]  = scores[(size_t)img * NM + idx];
            out[O_LB + base]  = (float)labels[(size_t)img * NM + idx];

            bool cfg = moj > 0.75f, cbg = moj < 0.25f;
            float cls = (!cfg && !cbg) ? (moj * 2.0f - 0.5f) : (cfg ? 1.0f : 0.0f);
            out[O_CLS + base] = cls;
            out[O_REG + base] = (moj > 0.55f) ? 1.0f : 0.0f;
        }
    }
}

extern "C" void kernel_launch(void* const* d_in, const int* in_sizes, int n_in,
                              void* d_out, int out_size, void* d_ws, size_t ws_size,
                              hipStream_t stream) {
    // identify inputs by element count (scores/labels tie resolved in dict order)
    const float* rois   = nullptr;
    const float* gts    = nullptr;
    const float* scores = nullptr;
    const int*   labels = nullptr;
    for (int i = 0; i < n_in; i++) {
        if (in_sizes[i] == NB * NM * 7)       rois = (const float*)d_in[i];
        else if (in_sizes[i] == NB * NGT * 8) gts  = (const float*)d_in[i];
        else if (in_sizes[i] == NB * NM) {
            if (!scores) scores = (const float*)d_in[i];
            else         labels = (const int*)d_in[i];
        }
    }
    float* out = (float*)d_out;  // 20480 f32, outputs concatenated in return order

    u32*   done = (u32*)d_ws;                                   // [0,4): ticket counter
    float* mo   = (float*)((char*)d_ws + 256);                  // 8192 f32
    int*   asg  = (int*)((char*)d_ws + 256 + NB * NM * 4);      // 8192 i32

    hipMemsetAsync(d_ws, 0, 4, stream);   // zero ticket counter (in-graph memset node)
    rcnn_one<<<GRID, BLK, 0, stream>>>(rois, gts, scores, labels, mo, asg, done, out);
}